// Round 6
// baseline (489.260 us; speedup 1.0000x reference)
//
#include <hip/hip_runtime.h>
#include <hip/hip_cooperative_groups.h>

namespace cg = cooperative_groups;

#define NPIX   (1024*1024)
#define NBATCH 16
#define NBINS  256
#define NSUB   4
#define SUBST  257              // sub-histogram stride (break bank aliasing)
#define BLKPB  32               // blocks per batch
#define GRID   (NBATCH*BLKPB)   // 512 blocks — 2/CU co-residency, safe for coop

typedef float v4f __attribute__((ext_vector_type(4)));

__device__ __forceinline__ float clamp01(float x) {
    return fminf(fmaxf(x, 0.0f), 1.0f);
}

// ---------------------------------------------------------------------------
// Single fused cooperative kernel:
//  phase 0: zero global hist (block 0 of each batch), grid sync
//  phase 1: per-batch Y histogram (LDS sub-hists -> global atomics), grid sync
//  phase 2: per-block LUT (redundant per block, from global hist, LDS scan)
//  phase 3: apply — YUV, LUT gather on trunc(y*255), YUV->RGB, nt stores
// img stays L3-resident between phase 1 and phase 3 (nt writes don't evict).
// ---------------------------------------------------------------------------
__global__ void __launch_bounds__(256, 2)
fused_kernel(const float* __restrict__ img, float* __restrict__ out,
             unsigned int* __restrict__ hist) {
    const int b   = blockIdx.x >> 5;    // batch  (BLKPB = 32)
    const int blk = blockIdx.x & 31;    // block within batch
    const int tid = threadIdx.x;

    __shared__ unsigned int lh[NSUB * SUBST];
    __shared__ float sc[NBINS];
    __shared__ int   li[NBINS];
    __shared__ float llut[NBINS];
    __shared__ float s_step;

    cg::grid_group grid = cg::this_grid();

    // ---- phase 0: zero this batch's global hist (agent-scope, cross-XCD safe)
    if (blk == 0)
        __hip_atomic_store(&hist[b * NBINS + tid], 0u,
                           __ATOMIC_RELAXED, __HIP_MEMORY_SCOPE_AGENT);
    for (int k = tid; k < NSUB * SUBST; k += 256) lh[k] = 0u;

    grid.sync();

    // ---- phase 1: histogram of Y
    const int sub = (tid & (NSUB - 1)) * SUBST;
    const float* base = img + (size_t)b * 3 * NPIX;
    const v4f* r4 = (const v4f*)(base);
    const v4f* g4 = (const v4f*)(base + NPIX);
    const v4f* b4 = (const v4f*)(base + 2 * NPIX);

    const int n4 = NPIX / 4;            // 262144 float4-triples per batch
    const int stride = BLKPB * 256;     // 8192 threads per batch
    for (int i = blk * 256 + tid; i < n4; i += stride) {
        v4f rv = r4[i], gv = g4[i], bv = b4[i];
#pragma unroll
        for (int k = 0; k < 4; ++k) {
            float r  = clamp01(rv[k]);
            float g  = clamp01(gv[k]);
            float bl = clamp01(bv[k]);
            float y = 0.299f * r + 0.587f * g + 0.114f * bl;
            float flat = y * 255.0f;                    // [0, 255]
            int bin = (int)floorf(flat * (256.0f / 255.0f));
            bin = bin > NBINS - 1 ? NBINS - 1 : bin;
            atomicAdd(&lh[sub + bin], 1u);
        }
    }
    __syncthreads();
    {
        unsigned int s = lh[0 * SUBST + tid] + lh[1 * SUBST + tid] +
                         lh[2 * SUBST + tid] + lh[3 * SUBST + tid];
        atomicAdd(&hist[b * NBINS + tid], s);           // device-scope
    }

    grid.sync();

    // ---- phase 2: LUT for this batch (every block, redundantly, in LDS)
    float hv = (float)__hip_atomic_load(&hist[b * NBINS + tid],
                                        __ATOMIC_RELAXED, __HIP_MEMORY_SCOPE_AGENT);
    sc[tid] = hv;
    li[tid] = (hv > 0.0f) ? tid : -1;
    __syncthreads();

    // Hillis-Steele inclusive scan (8 steps)
#pragma unroll
    for (int off = 1; off < NBINS; off <<= 1) {
        float v = (tid >= off) ? sc[tid - off] : 0.0f;
        __syncthreads();
        sc[tid] += v;
        __syncthreads();
    }
    // tree max-reduce for last nonzero bin (8 steps)
#pragma unroll
    for (int off = NBINS / 2; off > 0; off >>= 1) {
        int v = (tid < off) ? li[tid + off] : -1;
        __syncthreads();
        if (tid < off && v > li[tid]) li[tid] = v;
        __syncthreads();
    }

    {
        const float total = sc[NBINS - 1];
        int last = li[0];
        if (last < 0) last = NBINS - 1;
        const float hlast = sc[last] - (last > 0 ? sc[last - 1] : 0.0f);

        const float step = floorf((total - hlast) / 255.0f);
        const float half = floorf(step * 0.5f);
        const float safe = fmaxf(step, 1.0f);

        float l = (tid == 0) ? 0.0f : floorf((sc[tid - 1] + half) / safe);
        l = fminf(fmaxf(l, 0.0f), 255.0f);
        llut[tid] = l;
        if (tid == 0) s_step = step;
    }
    __syncthreads();

    // ---- phase 3: apply
    const float step = s_step;
    const bool identity = (step == 0.0f);

    float* obase = out + (size_t)b * 3 * NPIX;
    v4f* ro = (v4f*)(obase);
    v4f* go = (v4f*)(obase + NPIX);
    v4f* bo = (v4f*)(obase + 2 * NPIX);

    for (int i = blk * 256 + tid; i < n4; i += stride) {
        v4f rv = r4[i], gv = g4[i], bv = b4[i];
        v4f orr, org, orb;
#pragma unroll
        for (int k = 0; k < 4; ++k) {
            float r  = clamp01(rv[k]);
            float g  = clamp01(gv[k]);
            float bl = clamp01(bv[k]);
            float y = 0.299f * r + 0.587f * g + 0.114f * bl;
            float u = -0.147f * r - 0.289f * g + 0.436f * bl;
            float v = 0.615f * r - 0.515f * g - 0.1f * bl;

            float flat = y * 255.0f;
            int gi = (int)flat;                 // trunc == floor (flat >= 0)
            gi = gi > NBINS - 1 ? NBINS - 1 : gi;
            float ye = identity ? flat : llut[gi];
            ye = ye * (1.0f / 255.0f);

            orr[k] = ye + 1.14f * v;
            org[k] = ye - 0.396f * u - 0.581f * v;
            orb[k] = ye + 2.029f * u;
        }
        __builtin_nontemporal_store(orr, &ro[i]);
        __builtin_nontemporal_store(org, &go[i]);
        __builtin_nontemporal_store(orb, &bo[i]);
    }
}

extern "C" void kernel_launch(void* const* d_in, const int* in_sizes, int n_in,
                              void* d_out, int out_size, void* d_ws, size_t ws_size,
                              hipStream_t stream) {
    const float* img = (const float*)d_in[0];
    float* out = (float*)d_out;
    unsigned int* hist = (unsigned int*)d_ws;   // 16*256 u32, zeroed in-kernel

    void* args[] = { (void*)&img, (void*)&out, (void*)&hist };
    (void)hipLaunchCooperativeKernel((const void*)fused_kernel,
                                     dim3(GRID), dim3(256),
                                     args, 0, stream);
}